// Round 23
// baseline (719.668 us; speedup 1.0000x reference)
//
#include <hip/hip_runtime.h>
#include <hip/hip_bf16.h>

#define DEV __device__ __forceinline__

namespace {
constexpr size_t WS_XS   = 8192;
constexpr size_t WS_H3   = WS_XS + 294912;
constexpr size_t WS_XCUR = WS_H3 + 196608;
constexpr size_t WS_XPROJ= WS_XCUR + 196608;
constexpr size_t WS_HB0  = WS_XPROJ + 786432;
constexpr size_t WS_HB1  = WS_HB0 + 16384;
constexpr size_t WS_CB   = WS_HB1 + 16384;
constexpr size_t WS_YDEC = WS_CB + 16384;             // g2 table (4608) + bsum (2048 @ +8192)
constexpr size_t WS_YEMBB= WS_YDEC + 16384;
constexpr size_t WS_GB   = WS_YEMBB + 49152;
constexpr size_t WS_XC1  = WS_GB + 65536;
constexpr size_t WS_W12  = WS_XC1 + 16384;
constexpr size_t WS_ENDF = WS_W12 + 8192;
constexpr size_t A2_BYTES = 100663296ull;
constexpr int YN = 25165824;
}

typedef __bf16 b16x8 __attribute__((ext_vector_type(8)));
typedef float  f32x4 __attribute__((ext_vector_type(4)));

DEV float sigm(float x){ return 1.f/(1.f+expf(-x)); }

DEV unsigned short f2b(float x){ __hip_bfloat16 h=__float2bfloat16(x); return *reinterpret_cast<unsigned short*>(&h); }

DEV void gload16(const unsigned short* g, unsigned short* l){
  __builtin_amdgcn_global_load_lds((const __attribute__((address_space(1))) void*)g,
                                   (__attribute__((address_space(3))) void*)l, 16, 0, 0);
}

DEV float blockReduceSum256(float v, float* red){
  const int tid = threadIdx.x;
  red[tid]=v; __syncthreads();
  #pragma unroll
  for(int s=128;s>0;s>>=1){ if(tid<s) red[tid]+=red[tid+s]; __syncthreads(); }
  const float r = red[0]; __syncthreads();
  return r;
}

// fused 2-component block reduce: wave shuffle (no barriers) + 4 wave partials.
DEV float2 blockReduceSum2(float a, float b, float* red){
  #pragma unroll
  for(int off=32; off>0; off>>=1){
    a += __shfl_xor(a, off);
    b += __shfl_xor(b, off);
  }
  const int wid = threadIdx.x>>6;
  __syncthreads();
  if((threadIdx.x&63)==0){ red[wid*2]=a; red[wid*2+1]=b; }
  __syncthreads();
  float2 r;
  r.x = red[0]+red[2]+red[4]+red[6];
  r.y = red[1]+red[3]+red[5]+red[7];
  return r;
}

// ---------------- fused prepass: block 0 = mask pyramid, block 1 = W12 fold + g2 + bsum, blocks>=2 = Xs ----------------
__global__ __launch_bounds__(256) void k_pre(const float* __restrict__ xmask,
                                             const float* __restrict__ c1w, const float* __restrict__ c1b,
                                             const float* __restrict__ c2w,
                                             const float* __restrict__ rn_gate,
                                             const float* __restrict__ bih, const float* __restrict__ bhh,
                                             const float* __restrict__ Xstat, const float* __restrict__ static_w,
                                             float* __restrict__ ws,
                                             float* __restrict__ W12, float* __restrict__ WB,
                                             float* __restrict__ g2, float* __restrict__ bsum,
                                             float* __restrict__ XS){
  const int tid=threadIdx.x;
  if(blockIdx.x==0){
    float* R1  = ws;
    float* U1S = ws+2048;
    float* R2  = ws+4096;
    float* U2S = ws+4608;
    float* SC  = ws+5120;
    float* RU  = ws+5632;
    __shared__ float u1[2048];
    __shared__ float u2[512];
    __shared__ float red[256];
    for(int idx=tid; idx<2048; idx+=256){
      const int y=idx>>6, x=idx&63;
      const float s = xmask[(2*y)*128+2*x]+xmask[(2*y)*128+2*x+1]
                    + xmask[(2*y+1)*128+2*x]+xmask[(2*y+1)*128+2*x+1];
      const float u = fminf(fmaxf(s,0.f),1.f);
      const float r = 4.f/(s+1e-8f)*u;
      R1[idx]=r; U1S[idx]=u*u; RU[idx]=r*u*u; u1[idx]=u;
    }
    __syncthreads();
    for(int idx=tid; idx<512; idx+=256){
      const int y=idx>>5, x=idx&31;
      const float s = u1[(2*y)*64+2*x]+u1[(2*y)*64+2*x+1]+u1[(2*y+1)*64+2*x]+u1[(2*y+1)*64+2*x+1];
      const float u=fminf(fmaxf(s,0.f),1.f);
      R2[idx]=4.f/(s+1e-8f)*u; U2S[idx]=u*u; u2[idx]=u;
    }
    __syncthreads();
    float p=0; for(int idx=tid; idx<512; idx+=256) p+=u2[idx];
    const float s3 = blockReduceSum256(p,red);
    if(tid==0){ const float u=fminf(fmaxf(s3,0.f),1.f); SC[0]=512.f/(s3+1e-8f)*u; SC[1]=u; }
  } else if(blockIdx.x==1){
    const int oc=tid;
    for(int i=oc;i<4608;i+=256) g2[i]=2.f*sigm(rn_gate[i]);
    for(int i=oc;i<2048;i+=256) bsum[i]=bih[i]+bhh[i];
    float acc[16]={}; float accb[4]={};
    for(int ic=0;ic<128;ic++){
      const float4 w2=*(const float4*)&c2w[oc*512+ic*4];
      const float4 w1=*(const float4*)&c1w[ic*4];
      const float b1=c1b[ic];
      const float w2a[4]={w2.x,w2.y,w2.z,w2.w};
      const float w1a[4]={w1.x,w1.y,w1.z,w1.w};
      #pragma unroll
      for(int dydx=0;dydx<4;dydx++){
        const int dy=dydx>>1, dx=dydx&1;
        #pragma unroll
        for(int uv=0;uv<4;uv++){
          const int u=uv>>1, v=uv&1;
          acc[(2*dy+u)*4 + (2*dx+v)] = fmaf(w2a[dydx], w1a[uv], acc[(2*dy+u)*4+(2*dx+v)]);
        }
        accb[dydx] = fmaf(w2a[dydx], b1, accb[dydx]);
      }
    }
    #pragma unroll
    for(int t=0;t<16;t++) W12[oc*16+t]=acc[t];
    #pragma unroll
    for(int t=0;t<4;t++) WB[oc*4+t]=accb[t];
  } else {
    const int gid=(blockIdx.x-2)*256+tid;
    if(gid < 32*18*512){
      const int d = gid&511, row = gid>>9;
      const int b = row/18, si = row - b*18;
      const int s = si-11;
      float acc=0.f;
      #pragma unroll
      for(int j=0;j<12;j++){
        int idx = j - s; idx %= 12; if(idx<0) idx+=12;
        acc = fmaf(Xstat[b*12+idx], static_w[d*12+j], acc);
      }
      XS[gid]=acc;
    }
  }
}

// ---------------- fused conv1+conv2 ----------------
__global__ __launch_bounds__(256) void k_conv12(const float* __restrict__ Xauto, const float* __restrict__ xmask,
                                                const float* __restrict__ wsm,
                                                const float* __restrict__ W12, const float* __restrict__ WB,
                                                const float* __restrict__ c2b,
                                                unsigned short* __restrict__ A2){
  const int img=blockIdx.x, tid=threadIdx.x;
  __shared__ float S[64][132];
  __shared__ float u1s[2048];
  __shared__ float w12[4096];
  __shared__ float wb4[1024];
  __shared__ float r2s[512], u2s[512], cb[256];
  for(int i=tid;i<8192;i+=256){
    const int Y=i>>7, X=i&127;
    S[Y][X] = Xauto[(size_t)img*8192 + i] * xmask[i] * wsm[5632 + (Y>>1)*64 + (X>>1)];
  }
  for(int i=tid;i<2048;i+=256) u1s[i]=wsm[2048+i];
  for(int i=tid;i<4096;i+=256) w12[i]=W12[i];
  for(int i=tid;i<1024;i+=256) wb4[i]=WB[i];
  for(int i=tid;i<512;i+=256){ r2s[i]=wsm[4096+i]; u2s[i]=wsm[4608+i]; }
  if(tid<256) cb[tid]=c2b[tid];
  __syncthreads();
  float s16[2][16], us4[2][4], r2[2], u2[2];
  #pragma unroll
  for(int half=0;half<2;half++){
    const int p=tid+half*256;
    const int y2=p>>5, x2=p&31;
    #pragma unroll
    for(int ty=0;ty<4;ty++){
      const float4 v=*(const float4*)&S[4*y2+ty][4*x2];
      s16[half][ty*4+0]=v.x; s16[half][ty*4+1]=v.y; s16[half][ty*4+2]=v.z; s16[half][ty*4+3]=v.w;
    }
    #pragma unroll
    for(int dd=0;dd<4;dd++)
      us4[half][dd]=u1s[(2*y2+(dd>>1))*64 + (2*x2+(dd&1))];
    r2[half]=r2s[p]; u2[half]=u2s[p];
  }
  for(int oc=0;oc<256;oc++){
    const float4 w0=*(const float4*)&w12[oc*16];
    const float4 w1=*(const float4*)&w12[oc*16+4];
    const float4 w2=*(const float4*)&w12[oc*16+8];
    const float4 w3=*(const float4*)&w12[oc*16+12];
    const float4 wb=*(const float4*)&wb4[oc*4];
    const float cbo=cb[oc];
    #pragma unroll
    for(int half=0;half<2;half++){
      const float* s=s16[half];
      float a =  w0.x*s[0]+w0.y*s[1]+w0.z*s[2]+w0.w*s[3];
      a = fmaf(w1.x,s[4],fmaf(w1.y,s[5],fmaf(w1.z,s[6],fmaf(w1.w,s[7],a))));
      a = fmaf(w2.x,s[8],fmaf(w2.y,s[9],fmaf(w2.z,s[10],fmaf(w2.w,s[11],a))));
      a = fmaf(w3.x,s[12],fmaf(w3.y,s[13],fmaf(w3.z,s[14],fmaf(w3.w,s[15],a))));
      a += wb.x*us4[half][0]+wb.y*us4[half][1]+wb.z*us4[half][2]+wb.w*us4[half][3];
      const float v=(a*r2[half]+cbo)*u2[half];
      A2[(size_t)img*131072 + oc*512 + tid + half*256] = f2b(v);
    }
  }
}

// ---------------- MFMA bf16 GEMM: async gload_lds A (XOR-swizzled), chunk-major B (no pad), dbuf ----------------
// B stream: 2-deep register prefetch (bufBa/bufBb named sets, 2-step-unrolled K loop) to cover
// ~900-cycle HBM latency with a full iteration instead of one MFMA phase.
// MODE 1: conv3 split-K. BM=384 (c3w read once), BN=128, z=64 chunks of 2048.
// MODE 2: head. BM=192, BN=128 -> 80KB LDS = 2 blocks/CU.
// MODE 3: xproj. A f32 reg-staged+cvt (swizzled ds_write), B=wih f32, out [384][2048] + bsum.
template<int MODE, int BM, int BN, int NT>
__global__ __launch_bounds__(NT) void k_mfma(const unsigned short* __restrict__ Aq,
                                             const float* __restrict__ Bq,
                                             float* __restrict__ Cp,
                                             const float* __restrict__ bias0){
  constexpr int BK=64, CH=8;
  constexpr bool AF32 = (MODE==3);
  constexpr int NWN=2, NWM=(NT/64)/NWN;
  constexpr int RW=BM/NWM, CW=BN/NWN;
  constexpr int FM=RW/16, FN=CW/16;
  constexpr int NA=BM*CH/NT, NB=BN*CH/NT;
  constexpr int ABYTES=2*BM*BK*2, BBYTES=2*BN*BK*2;
  constexpr int CP=BN+4;
  constexpr int CSB=RW*CP*4;
  constexpr int SMB=(ABYTES+BBYTES>CSB)?(ABYTES+BBYTES):CSB;
  __shared__ __align__(16) char smem[SMB];
  unsigned short* lA=(unsigned short*)smem;
  unsigned short* lB=(unsigned short*)(smem+ABYTES);
  const int tid=threadIdx.x, lane=tid&63;
  const int w=tid>>6, wn=w&1, wm=w>>1;
  const int m0=blockIdx.y*BM, n0=blockIdx.x*BN;
  constexpr size_t lda=(MODE==1)?131072:512;
  constexpr size_t ldb=(MODE==1)?131072:512;
  int kbeg=0, kend=512;
  if constexpr(MODE==1){ kbeg=blockIdx.z*2048; kend=kbeg+2048; }

  f32x4 acc[FM][FN];
  #pragma unroll
  for(int i=0;i<FM;i++)
    #pragma unroll
    for(int j=0;j<FN;j++) acc[i][j]=f32x4{0.f,0.f,0.f,0.f};

  float4 bufBa[NB][2], bufBb[NB][2];
  float4 bufA[AF32?NA:1][2];
  auto stageA=[&](int k0, int buf){
    #pragma unroll
    for(int i=0;i<NA;i++){
      const int c=tid+i*NT, r=c>>3, gk=c&7;
      gload16(Aq + (size_t)(m0+r)*lda + k0 + ((gk ^ (r&7))<<3),
              lA + (size_t)buf*BM*64 + c*8);
    }
  };
  auto fetchA=[&](int k0){
    if constexpr(AF32){
      #pragma unroll
      for(int i=0;i<NA;i++){
        const int c=tid+i*NT, r=c>>3, gk=c&7;
        const float* p=(const float*)Aq + (size_t)(m0+r)*lda + k0+gk*8;
        bufA[i][0]=*(const float4*)p; bufA[i][1]=*(const float4*)(p+4);
      }
    }
  };
  auto commitA=[&](int buf){
    if constexpr(AF32){
      #pragma unroll
      for(int i=0;i<NA;i++){
        const int c=tid+i*NT, r=c>>3, gk=c&7;
        union { unsigned short us[8]; int4 q; } u;
        const float4 a=bufA[i][0], b=bufA[i][1];
        u.us[0]=f2b(a.x); u.us[1]=f2b(a.y); u.us[2]=f2b(a.z); u.us[3]=f2b(a.w);
        u.us[4]=f2b(b.x); u.us[5]=f2b(b.y); u.us[6]=f2b(b.z); u.us[7]=f2b(b.w);
        *(int4*)(lA + (size_t)buf*BM*64 + ((size_t)r*8 + (gk ^ (r&7)))*8)=u.q;
      }
    }
  };
  auto fetchBto=[&](float4 (&dst)[NB][2], int k0){
    #pragma unroll
    for(int i=0;i<NB;i++){
      const int c=tid+i*NT, r=c>>3, gk=c&7;
      const float* p=Bq + (size_t)(n0+r)*ldb + k0+gk*8;
      dst[i][0]=*(const float4*)p; dst[i][1]=*(const float4*)(p+4);
    }
  };
  auto commitBfrom=[&](float4 (&src)[NB][2], int buf){
    #pragma unroll
    for(int i=0;i<NB;i++){
      const int c=tid+i*NT, r=c>>3, gk=c&7;
      union { unsigned short us[8]; int4 q; } u;
      const float4 a=src[i][0], b=src[i][1];
      u.us[0]=f2b(a.x); u.us[1]=f2b(a.y); u.us[2]=f2b(a.z); u.us[3]=f2b(a.w);
      u.us[4]=f2b(b.x); u.us[5]=f2b(b.y); u.us[6]=f2b(b.z); u.us[7]=f2b(b.w);
      *(int4*)(lB + (size_t)buf*BN*64 + ((size_t)gk*BN + r)*8)=u.q;
    }
  };
  auto domfma=[&](int buf){
    #pragma unroll
    for(int ks=0; ks<2; ks++){
      const int gkr=ks*4+(lane>>4);
      b16x8 av[FM], bv[FN];
      #pragma unroll
      for(int i=0;i<FM;i++){
        const int row=wm*RW+i*16+(lane&15);
        av[i]=*(const b16x8*)(lA + (size_t)buf*BM*64 + row*64 + ((gkr ^ (row&7))<<3));
      }
      #pragma unroll
      for(int j=0;j<FN;j++){
        const int row=wn*CW+j*16+(lane&15);
        bv[j]=*(const b16x8*)(lB + (size_t)buf*BN*64 + ((size_t)gkr*BN + row)*8);
      }
      #pragma unroll
      for(int i=0;i<FM;i++)
        #pragma unroll
        for(int j=0;j<FN;j++)
          acc[i][j]=__builtin_amdgcn_mfma_f32_16x16x32_bf16(av[i],bv[j],acc[i][j],0,0,0);
    }
  };

  // prologue: lds0 <- step kbeg (A+B); bufBa <- fetch of kbeg+BK (in flight)
  if constexpr(AF32) fetchA(kbeg); else stageA(kbeg,0);
  fetchBto(bufBa, kbeg);
  if constexpr(AF32) commitA(0);
  commitBfrom(bufBa, 0);
  fetchBto(bufBa, kbeg+BK);
  __syncthreads();
  for(int k=kbeg; k<kend; k+=2*BK){
    // even step: consume lds0; bufBa holds k+BK (fetched one full step ago)
    {
      if(k+2*BK<kend) fetchBto(bufBb, k+2*BK);
      if constexpr(AF32) fetchA(k+BK); else stageA(k+BK, 1);
      commitBfrom(bufBa, 1);
      domfma(0);
      if constexpr(AF32) commitA(1);
      __syncthreads();
    }
    // odd step: consume lds1; bufBb holds k+2BK (if it exists)
    {
      const bool n1 = (k+2*BK)<kend;
      if(k+3*BK<kend) fetchBto(bufBa, k+3*BK);
      if(n1){
        if constexpr(AF32) fetchA(k+2*BK); else stageA(k+2*BK, 0);
        commitBfrom(bufBb, 0);
      }
      domfma(1);
      if(n1){ if constexpr(AF32) commitA(0); }
      __syncthreads();
    }
  }

  const int r4=(lane>>4)*4, cl=lane&15;
  float (*cs)[CP]=(float(*)[CP])smem;
  for(int ch=0; ch<NWM; ++ch){
    __syncthreads();
    if(wm==ch){
      #pragma unroll
      for(int i=0;i<FM;i++)
        #pragma unroll
        for(int j=0;j<FN;j++)
          #pragma unroll
          for(int ri=0;ri<4;ri++)
            cs[i*16+r4+ri][wn*CW+j*16+cl]=acc[i][j][ri];
    }
    __syncthreads();
    for(int idx=tid; idx<RW*(BN/4); idx+=NT){
      const int row=idx/(BN/4), q=idx%(BN/4);
      float4 v=*(float4*)&cs[row][q*4];
      const int gr=m0+ch*RW+row;
      if constexpr(MODE==1){
        *(float4*)&Cp[((size_t)blockIdx.z*384+gr)*512 + n0+q*4]=v;
      } else if constexpr(MODE==3){
        const float4 b=*(const float4*)&bias0[n0+q*4];
        v.x+=b.x; v.y+=b.y; v.z+=b.z; v.w+=b.w;
        *(float4*)&Cp[(size_t)gr*2048 + n0+q*4]=v;
      } else {
        const float4 b=*(const float4*)&bias0[n0+q*4];
        v.x+=b.x; v.y+=b.y; v.z+=b.z; v.w+=b.w;
        *(float4*)&Cp[(size_t)gr*131072 + n0+q*4]=v;
      }
    }
  }
}

// ---------------- variable-selection block (encoder, 384 blocks; fused conv3 split-K reduce) ----------------
__global__ __launch_bounds__(256) void k_varsel(
  const float* __restrict__ part, const float* __restrict__ c3b, const float* __restrict__ wsm,
  const float* __restrict__ Xcov, const float* __restrict__ cov_w,
  const float* __restrict__ Xs, const float* __restrict__ g2,
  const float* __restrict__ rn_scale, const float* __restrict__ rn_bias,
  const float* __restrict__ fc1_w, const float* __restrict__ fc1_b,
  const float* __restrict__ fc2_w, const float* __restrict__ fc2_b,
  const float* __restrict__ glu_w, const float* __restrict__ glu_b,
  const float* __restrict__ grn_s, const float* __restrict__ grn_b,
  const float* __restrict__ rs_gate, const float* __restrict__ rs_scale, const float* __restrict__ rs_bias,
  const float* __restrict__ lns, const float* __restrict__ lnb,
  float* __restrict__ outX, float* __restrict__ wgt_base)
{
  __shared__ float xin[9][512];
  __shared__ float red[256];
  __shared__ float obuf[512];
  __shared__ float muv[9], rsv[9], wsmx[9], hbuf9[9];
  const int tid=threadIdx.x, tk=blockIdx.x;
  const int b=tk/12, t=tk-b*12;
  const float* xs=Xs+((size_t)b*18+t)*512;
  const float* covrow=Xcov+(size_t)tk*8;
  float* orow=outX+(size_t)tk*512;
  float* wp=(t==11)? wgt_base+b*54 : nullptr;
  // xin[1..8] from cov embed (idx starts at 512 so vv>=1)
  for(int idx=512+tid; idx<4608; idx+=256){
    const int vv=idx>>9, d=idx&511;
    xin[vv][d] = fmaf(covrow[vv-1], cov_w[(vv-1)*512+d], xs[d]);
  }
  // xin[0] = h3 row (fused split-K reduce + pconv epilogue) + xs
  {
    const float r3=wsm[5120], u3=wsm[5121];
    const int d0=tid*2;
    float2 s={0.f,0.f};
    const float* pr=part + (size_t)tk*512 + d0;
    #pragma unroll 4
    for(int z=0;z<64;z++){
      const float2 v=*(const float2*)(pr + (size_t)z*196608);
      s.x+=v.x; s.y+=v.y;
    }
    xin[0][d0]  =(s.x*r3+c3b[d0])  *u3 + xs[d0];
    xin[0][d0+1]=(s.y*r3+c3b[d0+1])*u3 + xs[d0+1];
  }
  __syncthreads();
  // ---- batched LN stats for all 9 vv ----
  {
    float sa9[9], sb9[9];
    const int d0=tid*2;
    #pragma unroll
    for(int vv=0;vv<9;vv++){
      const float y0=xin[vv][d0]  *g2[vv*512+d0];
      const float y1=xin[vv][d0+1]*g2[vv*512+d0+1];
      sa9[vv]=y0+y1; sb9[vv]=y0*y0+y1*y1;
    }
    #pragma unroll
    for(int off=32; off>0; off>>=1){
      #pragma unroll
      for(int vv=0;vv<9;vv++){
        sa9[vv]+=__shfl_xor(sa9[vv],off);
        sb9[vv]+=__shfl_xor(sb9[vv],off);
      }
    }
    const int wid=tid>>6;
    if((tid&63)==0){
      #pragma unroll
      for(int vv=0;vv<9;vv++){ red[wid*18+vv]=sa9[vv]; red[wid*18+9+vv]=sb9[vv]; }
    }
    __syncthreads();
    if(tid<9){
      const float sA=red[tid]+red[18+tid]+red[36+tid]+red[54+tid];
      const float sB=red[9+tid]+red[27+tid]+red[45+tid]+red[63+tid];
      const float mu=sA*(1.f/512.f);
      const float var=sB*(1.f/512.f)-mu*mu;
      muv[tid]=mu; rsv[tid]=rsqrtf(var+1e-5f);
    }
  }
  // ---- fc1: per-thread partials, shuffle fold ----
  {
    float hp[9]={0,0,0,0,0,0,0,0,0};
    const float* flat=&xin[0][0];
    for(int i=tid;i<4608;i+=256){
      const float f=flat[i];
      #pragma unroll
      for(int j=0;j<9;j++) hp[j]=fmaf(f, fc1_w[j*4608+i], hp[j]);
    }
    #pragma unroll
    for(int off=32; off>0; off>>=1){
      #pragma unroll
      for(int j=0;j<9;j++) hp[j]+=__shfl_xor(hp[j],off);
    }
    const int wid=tid>>6;
    __syncthreads();
    if((tid&63)==0){
      #pragma unroll
      for(int j=0;j<9;j++) red[wid*9+j]=hp[j];
    }
    __syncthreads();
    if(tid<9) hbuf9[tid]=red[tid]+red[9+tid]+red[18+tid]+red[27+tid];
    __syncthreads();
  }
  if(tid==0){
    const float* flat=&xin[0][0];
    float rg[9];
    #pragma unroll
    for(int k=0;k<9;k++){
      const float pos=(float)k*575.875f;
      const int lo=(int)floorf(pos);
      const float fr=pos-(float)lo;
      int hi=lo+1; if(hi>4607)hi=4607;
      rg[k]=(flat[lo]*(1.f-fr)+flat[hi]*fr)*2.f*sigm(rs_gate[k]);
    }
    float mu=0.f; for(int k=0;k<9;k++) mu+=rg[k]; mu*=(1.f/9.f);
    float va=0.f; for(int k=0;k<9;k++){const float dd=rg[k]-mu; va+=dd*dd;} va*=(1.f/9.f);
    float rstd=rsqrtf(va+1e-5f);
    float resv[9];
    for(int k=0;k<9;k++) resv[k]=(rg[k]-mu)*rstd*rs_scale[k]+rs_bias[k];
    float h[9];
    for(int j=0;j<9;j++){ const float x=hbuf9[j]+fc1_b[j]; h[j]=x>0.f?x:expm1f(x); }
    float h2[9];
    for(int j=0;j<9;j++){ float s=fc2_b[j]; for(int k=0;k<9;k++) s=fmaf(h[k],fc2_w[j*9+k],s); h2[j]=s; }
    float lg[9];
    for(int j=0;j<9;j++){
      float sa=glu_b[j];   for(int k=0;k<9;k++) sa=fmaf(h2[k],glu_w[j*9+k],sa);
      float sg=glu_b[9+j]; for(int k=0;k<9;k++) sg=fmaf(h2[k],glu_w[(9+j)*9+k],sg);
      lg[j]=sa*sigm(sg)+resv[j];
    }
    mu=0.f; for(int k=0;k<9;k++) mu+=lg[k]; mu*=(1.f/9.f);
    va=0.f; for(int k=0;k<9;k++){const float dd=lg[k]-mu; va+=dd*dd;} va*=(1.f/9.f);
    rstd=rsqrtf(va+1e-5f);
    float lnv[9], mx=-1e30f;
    for(int k=0;k<9;k++){ lnv[k]=(lg[k]-mu)*rstd*grn_s[k]+grn_b[k]; mx=fmaxf(mx,lnv[k]); }
    float se=0.f;
    for(int k=0;k<9;k++){ lnv[k]=expf(lnv[k]-mx); se+=lnv[k]; }
    const float inv=1.f/se;
    for(int k=0;k<9;k++){ const float w=lnv[k]*inv; wsmx[k]=w; if(wp) wp[k]=w; }
  }
  __syncthreads();
  for(int d=tid; d<512; d+=256){
    float o=0.f;
    #pragma unroll
    for(int vv=0;vv<9;vv++){
      const float y=xin[vv][d]*g2[vv*512+d];
      const float vval=(y-muv[vv])*rsv[vv]*rn_scale[vv*512+d]+rn_bias[vv*512+d];
      o=fmaf(vval,wsmx[vv],o);
    }
    obuf[d]=o;
  }
  __syncthreads();
  float sa=0.f, sb=0.f;
  for(int d=tid;d<512;d+=256){ const float v=obuf[d]; sa+=v; sb+=v*v; }
  const float2 s2=blockReduceSum2(sa, sb, red);
  const float mu2=s2.x*(1.f/512.f);
  const float var2=s2.y*(1.f/512.f)-mu2*mu2;
  const float rstd2=rsqrtf(var2+1e-5f);
  for(int d=tid;d<512;d+=256) orow[d]=(obuf[d]-mu2)*rstd2*lns[d]+lnb[d];
}

// ---------------- one LSTM recurrence step (256 blocks, weights+h LDS-staged) ----------------
__global__ __launch_bounds__(256) void k_lstm_s(const float* __restrict__ xproj, const float* __restrict__ whh,
     const float* __restrict__ hr, float* __restrict__ hw, float* __restrict__ cg, int t){
  __shared__ float wlds[8][516];
  __shared__ float hlds[32][516];
  __shared__ float gv[32][9];
  const int bid=blockIdx.x, tid=threadIdx.x;
  const int j0=bid*2;
  for(int idx=tid; idx<1024; idx+=256){
    const int r2=idx>>7, k4=(idx&127)*4;
    const int gate2=r2>>1, jl2=r2&1;
    *(float4*)&wlds[r2][k4] = *(const float4*)&whh[(size_t)(gate2*512 + j0 + jl2)*512 + k4];
  }
  if(t>0){
    for(int idx=tid; idx<4096; idx+=256){
      const int rb=idx>>7, k4=(idx&127)*4;
      *(float4*)&hlds[rb][k4] = *(const float4*)&hr[rb*512+k4];
    }
  }
  __syncthreads();
  const int r=tid&7, b=tid>>3;
  const int gate=r>>1, jloc=r&1;
  float acc = xproj[((size_t)b*12+t)*2048 + gate*512 + j0 + jloc];
  if(t>0){
    float4 s={0.f,0.f,0.f,0.f};
    for(int k=0;k<512;k+=4){
      const float4 hk=*(const float4*)&hlds[b][k];
      const float4 wk=*(const float4*)&wlds[r][k];
      s.x=fmaf(hk.x,wk.x,s.x); s.y=fmaf(hk.y,wk.y,s.y);
      s.z=fmaf(hk.z,wk.z,s.z); s.w=fmaf(hk.w,wk.w,s.w);
    }
    acc+=(s.x+s.y)+(s.z+s.w);
  }
  gv[b][r]=acc;
  __syncthreads();
  if(tid<64){
    const int bb=tid>>1, jj=tid&1;
    const float gi=gv[bb][0+jj], gf=gv[bb][2+jj], gg=gv[bb][4+jj], go=gv[bb][6+jj];
    float c = (t==0) ? 0.f : cg[bb*512 + j0 + jj];
    c = sigm(gf)*c + sigm(gi)*tanhf(gg);
    cg[bb*512 + j0 + jj]=c;
    hw[bb*512 + j0 + jj]=sigm(go)*tanhf(c);
  }
}

// ---------------- decoder single-step LSTM (zero state), uses bsum ----------------
__global__ __launch_bounds__(256) void k_declstm(const float* __restrict__ Xc1, const float* __restrict__ wih,
        const float* __restrict__ bsum, float* __restrict__ hout){
  __shared__ float xs_[32][516];
  const int n=blockIdx.x, tid=threadIdx.x;
  for(int idx=tid; idx<16384; idx+=256){
    const int bb=idx>>9, k=idx&511;
    xs_[bb][k]=Xc1[bb*512+k];
  }
  __syncthreads();
  const int jl=tid>>4, bl=tid&15;
  const int j=n*16+jl;
  const float* wi=wih+(size_t)j*512;
  const float* wg=wih+(size_t)(1024+j)*512;
  const float* wo=wih+(size_t)(1536+j)*512;
  const float bi_=bsum[j];
  const float bg_=bsum[1024+j];
  const float bo_=bsum[1536+j];
  #pragma unroll
  for(int half=0; half<2; half++){
    const int b=bl+half*16;
    float gi=bi_, gg=bg_, go=bo_;
    for(int k=0;k<512;k+=4){
      const float4 xk=*(const float4*)&xs_[b][k];
      const float4 a0=*(const float4*)(wi+k);
      const float4 a1=*(const float4*)(wg+k);
      const float4 a2=*(const float4*)(wo+k);
      gi += xk.x*a0.x+xk.y*a0.y+xk.z*a0.z+xk.w*a0.w;
      gg += xk.x*a1.x+xk.y*a1.y+xk.z*a1.z+xk.w*a1.w;
      go += xk.x*a2.x+xk.y*a2.y+xk.z*a2.z+xk.w*a2.w;
    }
    const float c=sigm(gi)*tanhf(gg);
    hout[b*512+j]=sigm(go)*tanhf(c);
  }
}

// ---------------- fused ydec + decoder varsel (per-batch; grid 32) ----------------
__global__ __launch_bounds__(256) void k_ydvs(
  int l,
  const float* __restrict__ hb, const float* __restrict__ Xcov, const float* __restrict__ cov_w,
  const float* __restrict__ Xs, const float* __restrict__ g2,
  const float* __restrict__ rn_scale, const float* __restrict__ rn_bias,
  const float* __restrict__ fc1_w, const float* __restrict__ fc1_b,
  const float* __restrict__ fc2_w, const float* __restrict__ fc2_b,
  const float* __restrict__ glu_w, const float* __restrict__ glu_b,
  const float* __restrict__ grn_s, const float* __restrict__ grn_b,
  const float* __restrict__ rs_gate, const float* __restrict__ rs_scale, const float* __restrict__ rs_bias,
  const float* __restrict__ ln2s, const float* __restrict__ ln2b,
  const float* __restrict__ ln3s, const float* __restrict__ ln3b,
  float* __restrict__ outX, float* __restrict__ wgt_base, unsigned short* __restrict__ yembB)
{
  __shared__ float xin[9][512];
  __shared__ float red[256];
  __shared__ float obuf[512];
  __shared__ float ydl[512];
  __shared__ float muv[9], rsv[9], wsmx[9], hbuf9[9];
  const int tid=threadIdx.x, b=blockIdx.x;
  const float* xs=Xs+((size_t)b*18+12+l)*512;
  for(int d=tid;d<512;d+=256) obuf[d]=hb[b*512+d];
  __syncthreads();
  {
    float sa=0.f, sb=0.f;
    for(int d=tid;d<512;d+=256){ const float v=obuf[d]; sa+=v; sb+=v*v; }
    const float2 s2=blockReduceSum2(sa, sb, red);
    const float mu=s2.x*(1.f/512.f);
    const float var=s2.y*(1.f/512.f)-mu*mu;
    const float rstd=rsqrtf(var+1e-5f);
    for(int d=tid;d<512;d+=256){
      const float o=(obuf[d]-mu)*rstd*ln2s[d]+ln2b[d]+xs[d];
      ydl[d]=o;
      yembB[((size_t)b*6+l)*512+d]=f2b(o);
    }
  }
  __syncthreads();
  if(l==5) return;
  const float* covrow=Xcov+((size_t)b*12+11)*8;
  float* orow=outX+(size_t)b*512;
  float* wp=wgt_base+b*54+(l+1)*9;
  for(int idx=tid; idx<4608; idx+=256){
    const int vv=idx>>9, d=idx&511;
    const float base=xs[d];
    xin[vv][d] = (vv==0) ? (ydl[d]+base) : fmaf(covrow[vv-1], cov_w[(vv-1)*512+d], base);
  }
  __syncthreads();
  {
    float sa9[9], sb9[9];
    const int d0=tid*2;
    #pragma unroll
    for(int vv=0;vv<9;vv++){
      const float y0=xin[vv][d0]  *g2[vv*512+d0];
      const float y1=xin[vv][d0+1]*g2[vv*512+d0+1];
      sa9[vv]=y0+y1; sb9[vv]=y0*y0+y1*y1;
    }
    #pragma unroll
    for(int off=32; off>0; off>>=1){
      #pragma unroll
      for(int vv=0;vv<9;vv++){
        sa9[vv]+=__shfl_xor(sa9[vv],off);
        sb9[vv]+=__shfl_xor(sb9[vv],off);
      }
    }
    const int wid=tid>>6;
    if((tid&63)==0){
      #pragma unroll
      for(int vv=0;vv<9;vv++){ red[wid*18+vv]=sa9[vv]; red[wid*18+9+vv]=sb9[vv]; }
    }
    __syncthreads();
    if(tid<9){
      const float sA=red[tid]+red[18+tid]+red[36+tid]+red[54+tid];
      const float sB=red[9+tid]+red[27+tid]+red[45+tid]+red[63+tid];
      const float mu=sA*(1.f/512.f);
      const float var=sB*(1.f/512.f)-mu*mu;
      muv[tid]=mu; rsv[tid]=rsqrtf(var+1e-5f);
    }
  }
  {
    float hp[9]={0,0,0,0,0,0,0,0,0};
    const float* flat=&xin[0][0];
    for(int i=tid;i<4608;i+=256){
      const float f=flat[i];
      #pragma unroll
      for(int j=0;j<9;j++) hp[j]=fmaf(f, fc1_w[j*4608+i], hp[j]);
    }
    #pragma unroll
    for(int off=32; off>0; off>>=1){
      #pragma unroll
      for(int j=0;j<9;j++) hp[j]+=__shfl_xor(hp[j],off);
    }
    const int wid=tid>>6;
    __syncthreads();
    if((tid&63)==0){
      #pragma unroll
      for(int j=0;j<9;j++) red[wid*9+j]=hp[j];
    }
    __syncthreads();
    if(tid<9) hbuf9[tid]=red[tid]+red[9+tid]+red[18+tid]+red[27+tid];
    __syncthreads();
  }
  if(tid==0){
    const float* flat=&xin[0][0];
    float rg[9];
    #pragma unroll
    for(int k=0;k<9;k++){
      const float pos=(float)k*575.875f;
      const int lo=(int)floorf(pos);
      const float fr=pos-(float)lo;
      int hi=lo+1; if(hi>4607)hi=4607;
      rg[k]=(flat[lo]*(1.f-fr)+flat[hi]*fr)*2.f*sigm(rs_gate[k]);
    }
    float mu=0.f; for(int k=0;k<9;k++) mu+=rg[k]; mu*=(1.f/9.f);
    float va=0.f; for(int k=0;k<9;k++){const float dd=rg[k]-mu; va+=dd*dd;} va*=(1.f/9.f);
    float rstd=rsqrtf(va+1e-5f);
    float resv[9];
    for(int k=0;k<9;k++) resv[k]=(rg[k]-mu)*rstd*rs_scale[k]+rs_bias[k];
    float h[9];
    for(int j=0;j<9;j++){ const float x=hbuf9[j]+fc1_b[j]; h[j]=x>0.f?x:expm1f(x); }
    float h2[9];
    for(int j=0;j<9;j++){ float s=fc2_b[j]; for(int k=0;k<9;k++) s=fmaf(h[k],fc2_w[j*9+k],s); h2[j]=s; }
    float lg[9];
    for(int j=0;j<9;j++){
      float sa=glu_b[j];   for(int k=0;k<9;k++) sa=fmaf(h2[k],glu_w[j*9+k],sa);
      float sg=glu_b[9+j]; for(int k=0;k<9;k++) sg=fmaf(h2[k],glu_w[(9+j)*9+k],sg);
      lg[j]=sa*sigm(sg)+resv[j];
    }
    mu=0.f; for(int k=0;k<9;k++) mu+=lg[k]; mu*=(1.f/9.f);
    va=0.f; for(int k=0;k<9;k++){const float dd=lg[k]-mu; va+=dd*dd;} va*=(1.f/9.f);
    rstd=rsqrtf(va+1e-5f);
    float lnv[9], mx=-1e30f;
    for(int k=0;k<9;k++){ lnv[k]=(lg[k]-mu)*rstd*grn_s[k]+grn_b[k]; mx=fmaxf(mx,lnv[k]); }
    float se=0.f;
    for(int k=0;k<9;k++){ lnv[k]=expf(lnv[k]-mx); se+=lnv[k]; }
    const float inv=1.f/se;
    for(int k=0;k<9;k++){ const float w=lnv[k]*inv; wsmx[k]=w; wp[k]=w; }
  }
  __syncthreads();
  for(int d=tid; d<512; d+=256){
    float o=0.f;
    #pragma unroll
    for(int vv=0;vv<9;vv++){
      const float y=xin[vv][d]*g2[vv*512+d];
      const float vval=(y-muv[vv])*rsv[vv]*rn_scale[vv*512+d]+rn_bias[vv*512+d];
      o=fmaf(vval,wsmx[vv],o);
    }
    obuf[d]=o;
  }
  __syncthreads();
  float sa=0.f, sb=0.f;
  for(int d=tid;d<512;d+=256){ const float v=obuf[d]; sa+=v; sb+=v*v; }
  const float2 s2=blockReduceSum2(sa, sb, red);
  const float mu2=s2.x*(1.f/512.f);
  const float var2=s2.y*(1.f/512.f)-mu2*mu2;
  const float rstd2=rsqrtf(var2+1e-5f);
  for(int d=tid;d<512;d+=256) orow[d]=(obuf[d]-mu2)*rstd2*ln3s[d]+ln3b[d];
}

extern "C" void kernel_launch(void* const* d_in, const int* in_sizes, int n_in,
                              void* d_out, int out_size, void* d_ws, size_t ws_size,
                              hipStream_t stream){
  (void)in_sizes; (void)n_in; (void)out_size; (void)ws_size;
  const float* Xauto=(const float*)d_in[0];
  const float* Xcov =(const float*)d_in[1];
  const float* Xstat=(const float*)d_in[2];
  const float* xmask=(const float*)d_in[3];
  const float* c1w=(const float*)d_in[4];
  const float* c1b=(const float*)d_in[5];
  const float* c2w=(const float*)d_in[6];
  const float* c2b=(const float*)d_in[7];
  const float* c3w=(const float*)d_in[8];
  const float* c3b=(const float*)d_in[9];
  const float* cov_w=(const float*)d_in[10];
  const float* static_w=(const float*)d_in[11];
  const float* rn_gate=(const float*)d_in[12];
  const float* rn_scale=(const float*)d_in[13];
  const float* rn_bias=(const float*)d_in[14];
  const float* fc1_w=(const float*)d_in[15];
  const float* fc1_b=(const float*)d_in[16];
  const float* fc2_w=(const float*)d_in[17];
  const float* fc2_b=(const float*)d_in[18];
  const float* glu_w=(const float*)d_in[19];
  const float* glu_b=(const float*)d_in[20];
  const float* grn_s=(const float*)d_in[21];
  const float* grn_b=(const float*)d_in[22];
  const float* rs_gate=(const float*)d_in[23];
  const float* rs_scale=(const float*)d_in[24];
  const float* rs_bias=(const float*)d_in[25];
  const float* ln1s=(const float*)d_in[26];
  const float* ln1b=(const float*)d_in[27];
  const float* ln2s=(const float*)d_in[28];
  const float* ln2b=(const float*)d_in[29];
  const float* ln3s=(const float*)d_in[30];
  const float* ln3b=(const float*)d_in[31];
  const float* wih=(const float*)d_in[32];
  const float* whh=(const float*)d_in[33];
  const float* bih=(const float*)d_in[34];
  const float* bhh=(const float*)d_in[35];
  const float* head_w=(const float*)d_in[36];
  const float* head_b=(const float*)d_in[37];

  float* out=(float*)d_out;
  float* ws=(float*)d_ws;
  unsigned short* A2=(unsigned short*)((char*)d_ws + WS_ENDF*sizeof(float));
  float* part=(float*)((char*)d_ws + WS_ENDF*sizeof(float) + A2_BYTES);
  unsigned short* yembB=(unsigned short*)(ws+WS_YEMBB);
  float* g2=ws+WS_YDEC;            // 4608 floats
  float* bsum=ws+WS_YDEC+8192;     // 2048 floats

  const dim3 blk(256);
  k_pre<<<1154,blk,0,stream>>>(xmask, c1w, c1b, c2w, rn_gate, bih, bhh, Xstat, static_w,
                               ws, ws+WS_W12, ws+WS_W12+4096, g2, bsum, ws+WS_XS);
  k_conv12<<<384,blk,0,stream>>>(Xauto, xmask, ws, ws+WS_W12, ws+WS_W12+4096, c2b, A2);
  // conv3 split-K: BM=384 (c3w read once), BN=128, BK=64, z=64 chunks of 2048 (R21-best grid)
  k_mfma<1,384,128,512><<<dim3(4,1,64),dim3(512),0,stream>>>(A2, c3w, part, nullptr);
  // varsel with fused split-K reduce + pconv epilogue
  k_varsel<<<384,blk,0,stream>>>(part, c3b, ws, Xcov, cov_w, ws+WS_XS, g2,
      rn_scale,rn_bias, fc1_w,fc1_b,fc2_w,fc2_b, glu_w,glu_b, grn_s,grn_b,
      rs_gate,rs_scale,rs_bias, ln1s,ln1b, ws+WS_XCUR, out+YN);
  // xproj via MFMA (MODE 3): A=Xcur f32 reg-cvt, B=wih, bias=bsum
  k_mfma<3,192,128,512><<<dim3(16,2),dim3(512),0,stream>>>(
      (const unsigned short*)(const void*)(ws+WS_XCUR), wih, ws+WS_XPROJ, bsum);
  for(int t=0;t<12;t++){
    const float* hr = ws + ((t&1) ? WS_HB1 : WS_HB0);
    float* hw = ws + ((t&1) ? WS_HB0 : WS_HB1);
    k_lstm_s<<<256,blk,0,stream>>>(ws+WS_XPROJ, whh, hr, hw, ws+WS_CB, t);
  }
  for(int l=0;l<6;l++){
    if(l>0){
      k_declstm<<<32,blk,0,stream>>>(ws+WS_XC1, wih, bsum, ws+WS_HB0);
    }
    k_ydvs<<<32,blk,0,stream>>>(l, ws+WS_HB0, Xcov, cov_w, ws+WS_XS, g2,
        rn_scale,rn_bias, fc1_w,fc1_b,fc2_w,fc2_b, glu_w,glu_b, grn_s,grn_b,
        rs_gate,rs_scale,rs_bias, ln2s,ln2b, ln3s,ln3b,
        ws+WS_XC1, out+YN, yembB);
  }
  // head: BM=192, BN=128, BK=64 -> 80KB LDS = 2 blocks/CU, head_w read once
  k_mfma<2,192,128,512><<<dim3(1024,1),dim3(512),0,stream>>>(yembB, head_w, out, head_b);
}

// Round 24
// 708.825 us; speedup vs baseline: 1.0153x; 1.0153x over previous
//
#include <hip/hip_runtime.h>
#include <hip/hip_bf16.h>

#define DEV __device__ __forceinline__

namespace {
constexpr size_t WS_XS   = 8192;
constexpr size_t WS_H3   = WS_XS + 294912;
constexpr size_t WS_XCUR = WS_H3 + 196608;
constexpr size_t WS_XPROJ= WS_XCUR + 196608;
constexpr size_t WS_HB0  = WS_XPROJ + 786432;
constexpr size_t WS_HB1  = WS_HB0 + 16384;
constexpr size_t WS_CB   = WS_HB1 + 16384;
constexpr size_t WS_YDEC = WS_CB + 16384;             // g2 table (4608) + bsum (2048 @ +8192)
constexpr size_t WS_YEMBB= WS_YDEC + 16384;
constexpr size_t WS_GB   = WS_YEMBB + 49152;
constexpr size_t WS_XC1  = WS_GB + 65536;
constexpr size_t WS_W12  = WS_XC1 + 16384;
constexpr size_t WS_ENDF = WS_W12 + 8192;
constexpr size_t A2_BYTES = 100663296ull;
constexpr int YN = 25165824;
}

typedef __bf16 b16x8 __attribute__((ext_vector_type(8)));
typedef float  f32x4 __attribute__((ext_vector_type(4)));

DEV float sigm(float x){ return 1.f/(1.f+expf(-x)); }

DEV unsigned short f2b(float x){ __hip_bfloat16 h=__float2bfloat16(x); return *reinterpret_cast<unsigned short*>(&h); }

DEV void gload16(const unsigned short* g, unsigned short* l){
  __builtin_amdgcn_global_load_lds((const __attribute__((address_space(1))) void*)g,
                                   (__attribute__((address_space(3))) void*)l, 16, 0, 0);
}

DEV float blockReduceSum256(float v, float* red){
  const int tid = threadIdx.x;
  red[tid]=v; __syncthreads();
  #pragma unroll
  for(int s=128;s>0;s>>=1){ if(tid<s) red[tid]+=red[tid+s]; __syncthreads(); }
  const float r = red[0]; __syncthreads();
  return r;
}

// fused 2-component block reduce: wave shuffle (no barriers) + 4 wave partials.
DEV float2 blockReduceSum2(float a, float b, float* red){
  #pragma unroll
  for(int off=32; off>0; off>>=1){
    a += __shfl_xor(a, off);
    b += __shfl_xor(b, off);
  }
  const int wid = threadIdx.x>>6;
  __syncthreads();
  if((threadIdx.x&63)==0){ red[wid*2]=a; red[wid*2+1]=b; }
  __syncthreads();
  float2 r;
  r.x = red[0]+red[2]+red[4]+red[6];
  r.y = red[1]+red[3]+red[5]+red[7];
  return r;
}

// ---------------- fused prepass: block 0 = mask pyramid, block 1 = W12 fold + g2 + bsum, blocks>=2 = Xs ----------------
__global__ __launch_bounds__(256) void k_pre(const float* __restrict__ xmask,
                                             const float* __restrict__ c1w, const float* __restrict__ c1b,
                                             const float* __restrict__ c2w,
                                             const float* __restrict__ rn_gate,
                                             const float* __restrict__ bih, const float* __restrict__ bhh,
                                             const float* __restrict__ Xstat, const float* __restrict__ static_w,
                                             float* __restrict__ ws,
                                             float* __restrict__ W12, float* __restrict__ WB,
                                             float* __restrict__ g2, float* __restrict__ bsum,
                                             float* __restrict__ XS){
  const int tid=threadIdx.x;
  if(blockIdx.x==0){
    float* R1  = ws;
    float* U1S = ws+2048;
    float* R2  = ws+4096;
    float* U2S = ws+4608;
    float* SC  = ws+5120;
    float* RU  = ws+5632;
    __shared__ float u1[2048];
    __shared__ float u2[512];
    __shared__ float red[256];
    for(int idx=tid; idx<2048; idx+=256){
      const int y=idx>>6, x=idx&63;
      const float s = xmask[(2*y)*128+2*x]+xmask[(2*y)*128+2*x+1]
                    + xmask[(2*y+1)*128+2*x]+xmask[(2*y+1)*128+2*x+1];
      const float u = fminf(fmaxf(s,0.f),1.f);
      const float r = 4.f/(s+1e-8f)*u;
      R1[idx]=r; U1S[idx]=u*u; RU[idx]=r*u*u; u1[idx]=u;
    }
    __syncthreads();
    for(int idx=tid; idx<512; idx+=256){
      const int y=idx>>5, x=idx&31;
      const float s = u1[(2*y)*64+2*x]+u1[(2*y)*64+2*x+1]+u1[(2*y+1)*64+2*x]+u1[(2*y+1)*64+2*x+1];
      const float u=fminf(fmaxf(s,0.f),1.f);
      R2[idx]=4.f/(s+1e-8f)*u; U2S[idx]=u*u; u2[idx]=u;
    }
    __syncthreads();
    float p=0; for(int idx=tid; idx<512; idx+=256) p+=u2[idx];
    const float s3 = blockReduceSum256(p,red);
    if(tid==0){ const float u=fminf(fmaxf(s3,0.f),1.f); SC[0]=512.f/(s3+1e-8f)*u; SC[1]=u; }
  } else if(blockIdx.x==1){
    const int oc=tid;
    for(int i=oc;i<4608;i+=256) g2[i]=2.f*sigm(rn_gate[i]);
    for(int i=oc;i<2048;i+=256) bsum[i]=bih[i]+bhh[i];
    float acc[16]={}; float accb[4]={};
    for(int ic=0;ic<128;ic++){
      const float4 w2=*(const float4*)&c2w[oc*512+ic*4];
      const float4 w1=*(const float4*)&c1w[ic*4];
      const float b1=c1b[ic];
      const float w2a[4]={w2.x,w2.y,w2.z,w2.w};
      const float w1a[4]={w1.x,w1.y,w1.z,w1.w};
      #pragma unroll
      for(int dydx=0;dydx<4;dydx++){
        const int dy=dydx>>1, dx=dydx&1;
        #pragma unroll
        for(int uv=0;uv<4;uv++){
          const int u=uv>>1, v=uv&1;
          acc[(2*dy+u)*4 + (2*dx+v)] = fmaf(w2a[dydx], w1a[uv], acc[(2*dy+u)*4+(2*dx+v)]);
        }
        accb[dydx] = fmaf(w2a[dydx], b1, accb[dydx]);
      }
    }
    #pragma unroll
    for(int t=0;t<16;t++) W12[oc*16+t]=acc[t];
    #pragma unroll
    for(int t=0;t<4;t++) WB[oc*4+t]=accb[t];
  } else {
    const int gid=(blockIdx.x-2)*256+tid;
    if(gid < 32*18*512){
      const int d = gid&511, row = gid>>9;
      const int b = row/18, si = row - b*18;
      const int s = si-11;
      float acc=0.f;
      #pragma unroll
      for(int j=0;j<12;j++){
        int idx = j - s; idx %= 12; if(idx<0) idx+=12;
        acc = fmaf(Xstat[b*12+idx], static_w[d*12+j], acc);
      }
      XS[gid]=acc;
    }
  }
}

// ---------------- fused conv1+conv2 ----------------
__global__ __launch_bounds__(256) void k_conv12(const float* __restrict__ Xauto, const float* __restrict__ xmask,
                                                const float* __restrict__ wsm,
                                                const float* __restrict__ W12, const float* __restrict__ WB,
                                                const float* __restrict__ c2b,
                                                unsigned short* __restrict__ A2){
  const int img=blockIdx.x, tid=threadIdx.x;
  __shared__ float S[64][132];
  __shared__ float u1s[2048];
  __shared__ float w12[4096];
  __shared__ float wb4[1024];
  __shared__ float r2s[512], u2s[512], cb[256];
  for(int i=tid;i<8192;i+=256){
    const int Y=i>>7, X=i&127;
    S[Y][X] = Xauto[(size_t)img*8192 + i] * xmask[i] * wsm[5632 + (Y>>1)*64 + (X>>1)];
  }
  for(int i=tid;i<2048;i+=256) u1s[i]=wsm[2048+i];
  for(int i=tid;i<4096;i+=256) w12[i]=W12[i];
  for(int i=tid;i<1024;i+=256) wb4[i]=WB[i];
  for(int i=tid;i<512;i+=256){ r2s[i]=wsm[4096+i]; u2s[i]=wsm[4608+i]; }
  if(tid<256) cb[tid]=c2b[tid];
  __syncthreads();
  float s16[2][16], us4[2][4], r2[2], u2[2];
  #pragma unroll
  for(int half=0;half<2;half++){
    const int p=tid+half*256;
    const int y2=p>>5, x2=p&31;
    #pragma unroll
    for(int ty=0;ty<4;ty++){
      const float4 v=*(const float4*)&S[4*y2+ty][4*x2];
      s16[half][ty*4+0]=v.x; s16[half][ty*4+1]=v.y; s16[half][ty*4+2]=v.z; s16[half][ty*4+3]=v.w;
    }
    #pragma unroll
    for(int dd=0;dd<4;dd++)
      us4[half][dd]=u1s[(2*y2+(dd>>1))*64 + (2*x2+(dd&1))];
    r2[half]=r2s[p]; u2[half]=u2s[p];
  }
  for(int oc=0;oc<256;oc++){
    const float4 w0=*(const float4*)&w12[oc*16];
    const float4 w1=*(const float4*)&w12[oc*16+4];
    const float4 w2=*(const float4*)&w12[oc*16+8];
    const float4 w3=*(const float4*)&w12[oc*16+12];
    const float4 wb=*(const float4*)&wb4[oc*4];
    const float cbo=cb[oc];
    #pragma unroll
    for(int half=0;half<2;half++){
      const float* s=s16[half];
      float a =  w0.x*s[0]+w0.y*s[1]+w0.z*s[2]+w0.w*s[3];
      a = fmaf(w1.x,s[4],fmaf(w1.y,s[5],fmaf(w1.z,s[6],fmaf(w1.w,s[7],a))));
      a = fmaf(w2.x,s[8],fmaf(w2.y,s[9],fmaf(w2.z,s[10],fmaf(w2.w,s[11],a))));
      a = fmaf(w3.x,s[12],fmaf(w3.y,s[13],fmaf(w3.z,s[14],fmaf(w3.w,s[15],a))));
      a += wb.x*us4[half][0]+wb.y*us4[half][1]+wb.z*us4[half][2]+wb.w*us4[half][3];
      const float v=(a*r2[half]+cbo)*u2[half];
      A2[(size_t)img*131072 + oc*512 + tid + half*256] = f2b(v);
    }
  }
}

// ---------------- MFMA bf16 GEMM: async gload_lds A (XOR-swizzled), chunk-major B (no pad), dbuf ----------------
// MODE 1: conv3 split-K. BM=384 (c3w read once), BN=128, z=64 chunks of 2048. NT=1024 (16 waves/CU).
// MODE 2: head. BM=192, BN=128 -> 80KB LDS = 2 blocks/CU.
// MODE 3: xproj. A f32 reg-staged+cvt (swizzled ds_write), B=wih f32, out [384][2048] + bsum.
template<int MODE, int BM, int BN, int NT>
__global__ __launch_bounds__(NT) void k_mfma(const unsigned short* __restrict__ Aq,
                                             const float* __restrict__ Bq,
                                             float* __restrict__ Cp,
                                             const float* __restrict__ bias0){
  constexpr int BK=64, CH=8;
  constexpr bool AF32 = (MODE==3);
  constexpr int NWN=2, NWM=(NT/64)/NWN;
  constexpr int RW=BM/NWM, CW=BN/NWN;
  constexpr int FM=RW/16, FN=CW/16;
  constexpr int NA=BM*CH/NT, NB=BN*CH/NT;
  constexpr int ABYTES=2*BM*BK*2, BBYTES=2*BN*BK*2;
  constexpr int CP=BN+4;
  constexpr int CSB=RW*CP*4;
  constexpr int SMB=(ABYTES+BBYTES>CSB)?(ABYTES+BBYTES):CSB;
  __shared__ __align__(16) char smem[SMB];
  unsigned short* lA=(unsigned short*)smem;
  unsigned short* lB=(unsigned short*)(smem+ABYTES);
  const int tid=threadIdx.x, lane=tid&63;
  const int w=tid>>6, wn=w&1, wm=w>>1;
  const int m0=blockIdx.y*BM, n0=blockIdx.x*BN;
  constexpr size_t lda=(MODE==1)?131072:512;
  constexpr size_t ldb=(MODE==1)?131072:512;
  int kbeg=0, kend=512;
  if constexpr(MODE==1){ kbeg=blockIdx.z*2048; kend=kbeg+2048; }

  f32x4 acc[FM][FN];
  #pragma unroll
  for(int i=0;i<FM;i++)
    #pragma unroll
    for(int j=0;j<FN;j++) acc[i][j]=f32x4{0.f,0.f,0.f,0.f};

  float4 bufB[NB][2];
  float4 bufA[AF32?NA:1][2];
  auto stageA=[&](int k0, int buf){
    #pragma unroll
    for(int i=0;i<NA;i++){
      const int c=tid+i*NT, r=c>>3, gk=c&7;
      gload16(Aq + (size_t)(m0+r)*lda + k0 + ((gk ^ (r&7))<<3),
              lA + (size_t)buf*BM*64 + c*8);
    }
  };
  auto fetchA=[&](int k0){
    if constexpr(AF32){
      #pragma unroll
      for(int i=0;i<NA;i++){
        const int c=tid+i*NT, r=c>>3, gk=c&7;
        const float* p=(const float*)Aq + (size_t)(m0+r)*lda + k0+gk*8;
        bufA[i][0]=*(const float4*)p; bufA[i][1]=*(const float4*)(p+4);
      }
    }
  };
  auto commitA=[&](int buf){
    if constexpr(AF32){
      #pragma unroll
      for(int i=0;i<NA;i++){
        const int c=tid+i*NT, r=c>>3, gk=c&7;
        union { unsigned short us[8]; int4 q; } u;
        const float4 a=bufA[i][0], b=bufA[i][1];
        u.us[0]=f2b(a.x); u.us[1]=f2b(a.y); u.us[2]=f2b(a.z); u.us[3]=f2b(a.w);
        u.us[4]=f2b(b.x); u.us[5]=f2b(b.y); u.us[6]=f2b(b.z); u.us[7]=f2b(b.w);
        *(int4*)(lA + (size_t)buf*BM*64 + ((size_t)r*8 + (gk ^ (r&7)))*8)=u.q;
      }
    }
  };
  auto fetchB=[&](int k0){
    #pragma unroll
    for(int i=0;i<NB;i++){
      const int c=tid+i*NT, r=c>>3, gk=c&7;
      const float* p=Bq + (size_t)(n0+r)*ldb + k0+gk*8;
      bufB[i][0]=*(const float4*)p; bufB[i][1]=*(const float4*)(p+4);
    }
  };
  auto commitB=[&](int buf){
    #pragma unroll
    for(int i=0;i<NB;i++){
      const int c=tid+i*NT, r=c>>3, gk=c&7;
      union { unsigned short us[8]; int4 q; } u;
      const float4 a=bufB[i][0], b=bufB[i][1];
      u.us[0]=f2b(a.x); u.us[1]=f2b(a.y); u.us[2]=f2b(a.z); u.us[3]=f2b(a.w);
      u.us[4]=f2b(b.x); u.us[5]=f2b(b.y); u.us[6]=f2b(b.z); u.us[7]=f2b(b.w);
      *(int4*)(lB + (size_t)buf*BN*64 + ((size_t)gk*BN + r)*8)=u.q;
    }
  };

  int cur=0;
  if constexpr(AF32) fetchA(kbeg); else stageA(kbeg,0);
  fetchB(kbeg);
  if constexpr(AF32) commitA(0);
  commitB(0);
  __syncthreads();
  for(int k0=kbeg; k0<kend; k0+=BK){
    const bool nxt=(k0+BK<kend);
    if(nxt){
      if constexpr(AF32) fetchA(k0+BK); else stageA(k0+BK, cur^1);
      fetchB(k0+BK);
    }
    #pragma unroll
    for(int ks=0; ks<2; ks++){
      const int gkr=ks*4+(lane>>4);
      b16x8 av[FM], bv[FN];
      #pragma unroll
      for(int i=0;i<FM;i++){
        const int row=wm*RW+i*16+(lane&15);
        av[i]=*(const b16x8*)(lA + (size_t)cur*BM*64 + row*64 + ((gkr ^ (row&7))<<3));
      }
      #pragma unroll
      for(int j=0;j<FN;j++){
        const int row=wn*CW+j*16+(lane&15);
        bv[j]=*(const b16x8*)(lB + (size_t)cur*BN*64 + ((size_t)gkr*BN + row)*8);
      }
      #pragma unroll
      for(int i=0;i<FM;i++)
        #pragma unroll
        for(int j=0;j<FN;j++)
          acc[i][j]=__builtin_amdgcn_mfma_f32_16x16x32_bf16(av[i],bv[j],acc[i][j],0,0,0);
    }
    if(nxt){
      if constexpr(AF32) commitA(cur^1);
      commitB(cur^1);
    }
    __syncthreads();
    cur^=1;
  }

  const int r4=(lane>>4)*4, cl=lane&15;
  float (*cs)[CP]=(float(*)[CP])smem;
  for(int ch=0; ch<NWM; ++ch){
    __syncthreads();
    if(wm==ch){
      #pragma unroll
      for(int i=0;i<FM;i++)
        #pragma unroll
        for(int j=0;j<FN;j++)
          #pragma unroll
          for(int ri=0;ri<4;ri++)
            cs[i*16+r4+ri][wn*CW+j*16+cl]=acc[i][j][ri];
    }
    __syncthreads();
    for(int idx=tid; idx<RW*(BN/4); idx+=NT){
      const int row=idx/(BN/4), q=idx%(BN/4);
      float4 v=*(float4*)&cs[row][q*4];
      const int gr=m0+ch*RW+row;
      if constexpr(MODE==1){
        *(float4*)&Cp[((size_t)blockIdx.z*384+gr)*512 + n0+q*4]=v;
      } else if constexpr(MODE==3){
        const float4 b=*(const float4*)&bias0[n0+q*4];
        v.x+=b.x; v.y+=b.y; v.z+=b.z; v.w+=b.w;
        *(float4*)&Cp[(size_t)gr*2048 + n0+q*4]=v;
      } else {
        const float4 b=*(const float4*)&bias0[n0+q*4];
        v.x+=b.x; v.y+=b.y; v.z+=b.z; v.w+=b.w;
        *(float4*)&Cp[(size_t)gr*131072 + n0+q*4]=v;
      }
    }
  }
}

// ---------------- variable-selection block (encoder, 384 blocks; fused conv3 split-K reduce) ----------------
__global__ __launch_bounds__(256) void k_varsel(
  const float* __restrict__ part, const float* __restrict__ c3b, const float* __restrict__ wsm,
  const float* __restrict__ Xcov, const float* __restrict__ cov_w,
  const float* __restrict__ Xs, const float* __restrict__ g2,
  const float* __restrict__ rn_scale, const float* __restrict__ rn_bias,
  const float* __restrict__ fc1_w, const float* __restrict__ fc1_b,
  const float* __restrict__ fc2_w, const float* __restrict__ fc2_b,
  const float* __restrict__ glu_w, const float* __restrict__ glu_b,
  const float* __restrict__ grn_s, const float* __restrict__ grn_b,
  const float* __restrict__ rs_gate, const float* __restrict__ rs_scale, const float* __restrict__ rs_bias,
  const float* __restrict__ lns, const float* __restrict__ lnb,
  float* __restrict__ outX, float* __restrict__ wgt_base)
{
  __shared__ float xin[9][512];
  __shared__ float red[256];
  __shared__ float obuf[512];
  __shared__ float muv[9], rsv[9], wsmx[9], hbuf9[9];
  const int tid=threadIdx.x, tk=blockIdx.x;
  const int b=tk/12, t=tk-b*12;
  const float* xs=Xs+((size_t)b*18+t)*512;
  const float* covrow=Xcov+(size_t)tk*8;
  float* orow=outX+(size_t)tk*512;
  float* wp=(t==11)? wgt_base+b*54 : nullptr;
  // xin[1..8] from cov embed (idx starts at 512 so vv>=1)
  for(int idx=512+tid; idx<4608; idx+=256){
    const int vv=idx>>9, d=idx&511;
    xin[vv][d] = fmaf(covrow[vv-1], cov_w[(vv-1)*512+d], xs[d]);
  }
  // xin[0] = h3 row (fused split-K reduce + pconv epilogue) + xs
  {
    const float r3=wsm[5120], u3=wsm[5121];
    const int d0=tid*2;
    float2 s={0.f,0.f};
    const float* pr=part + (size_t)tk*512 + d0;
    #pragma unroll 4
    for(int z=0;z<64;z++){
      const float2 v=*(const float2*)(pr + (size_t)z*196608);
      s.x+=v.x; s.y+=v.y;
    }
    xin[0][d0]  =(s.x*r3+c3b[d0])  *u3 + xs[d0];
    xin[0][d0+1]=(s.y*r3+c3b[d0+1])*u3 + xs[d0+1];
  }
  __syncthreads();
  // ---- batched LN stats for all 9 vv ----
  {
    float sa9[9], sb9[9];
    const int d0=tid*2;
    #pragma unroll
    for(int vv=0;vv<9;vv++){
      const float y0=xin[vv][d0]  *g2[vv*512+d0];
      const float y1=xin[vv][d0+1]*g2[vv*512+d0+1];
      sa9[vv]=y0+y1; sb9[vv]=y0*y0+y1*y1;
    }
    #pragma unroll
    for(int off=32; off>0; off>>=1){
      #pragma unroll
      for(int vv=0;vv<9;vv++){
        sa9[vv]+=__shfl_xor(sa9[vv],off);
        sb9[vv]+=__shfl_xor(sb9[vv],off);
      }
    }
    const int wid=tid>>6;
    if((tid&63)==0){
      #pragma unroll
      for(int vv=0;vv<9;vv++){ red[wid*18+vv]=sa9[vv]; red[wid*18+9+vv]=sb9[vv]; }
    }
    __syncthreads();
    if(tid<9){
      const float sA=red[tid]+red[18+tid]+red[36+tid]+red[54+tid];
      const float sB=red[9+tid]+red[27+tid]+red[45+tid]+red[63+tid];
      const float mu=sA*(1.f/512.f);
      const float var=sB*(1.f/512.f)-mu*mu;
      muv[tid]=mu; rsv[tid]=rsqrtf(var+1e-5f);
    }
  }
  // ---- fc1: per-thread partials, shuffle fold ----
  {
    float hp[9]={0,0,0,0,0,0,0,0,0};
    const float* flat=&xin[0][0];
    for(int i=tid;i<4608;i+=256){
      const float f=flat[i];
      #pragma unroll
      for(int j=0;j<9;j++) hp[j]=fmaf(f, fc1_w[j*4608+i], hp[j]);
    }
    #pragma unroll
    for(int off=32; off>0; off>>=1){
      #pragma unroll
      for(int j=0;j<9;j++) hp[j]+=__shfl_xor(hp[j],off);
    }
    const int wid=tid>>6;
    __syncthreads();
    if((tid&63)==0){
      #pragma unroll
      for(int j=0;j<9;j++) red[wid*9+j]=hp[j];
    }
    __syncthreads();
    if(tid<9) hbuf9[tid]=red[tid]+red[9+tid]+red[18+tid]+red[27+tid];
    __syncthreads();
  }
  if(tid==0){
    const float* flat=&xin[0][0];
    float rg[9];
    #pragma unroll
    for(int k=0;k<9;k++){
      const float pos=(float)k*575.875f;
      const int lo=(int)floorf(pos);
      const float fr=pos-(float)lo;
      int hi=lo+1; if(hi>4607)hi=4607;
      rg[k]=(flat[lo]*(1.f-fr)+flat[hi]*fr)*2.f*sigm(rs_gate[k]);
    }
    float mu=0.f; for(int k=0;k<9;k++) mu+=rg[k]; mu*=(1.f/9.f);
    float va=0.f; for(int k=0;k<9;k++){const float dd=rg[k]-mu; va+=dd*dd;} va*=(1.f/9.f);
    float rstd=rsqrtf(va+1e-5f);
    float resv[9];
    for(int k=0;k<9;k++) resv[k]=(rg[k]-mu)*rstd*rs_scale[k]+rs_bias[k];
    float h[9];
    for(int j=0;j<9;j++){ const float x=hbuf9[j]+fc1_b[j]; h[j]=x>0.f?x:expm1f(x); }
    float h2[9];
    for(int j=0;j<9;j++){ float s=fc2_b[j]; for(int k=0;k<9;k++) s=fmaf(h[k],fc2_w[j*9+k],s); h2[j]=s; }
    float lg[9];
    for(int j=0;j<9;j++){
      float sa=glu_b[j];   for(int k=0;k<9;k++) sa=fmaf(h2[k],glu_w[j*9+k],sa);
      float sg=glu_b[9+j]; for(int k=0;k<9;k++) sg=fmaf(h2[k],glu_w[(9+j)*9+k],sg);
      lg[j]=sa*sigm(sg)+resv[j];
    }
    mu=0.f; for(int k=0;k<9;k++) mu+=lg[k]; mu*=(1.f/9.f);
    va=0.f; for(int k=0;k<9;k++){const float dd=lg[k]-mu; va+=dd*dd;} va*=(1.f/9.f);
    rstd=rsqrtf(va+1e-5f);
    float lnv[9], mx=-1e30f;
    for(int k=0;k<9;k++){ lnv[k]=(lg[k]-mu)*rstd*grn_s[k]+grn_b[k]; mx=fmaxf(mx,lnv[k]); }
    float se=0.f;
    for(int k=0;k<9;k++){ lnv[k]=expf(lnv[k]-mx); se+=lnv[k]; }
    const float inv=1.f/se;
    for(int k=0;k<9;k++){ const float w=lnv[k]*inv; wsmx[k]=w; if(wp) wp[k]=w; }
  }
  __syncthreads();
  for(int d=tid; d<512; d+=256){
    float o=0.f;
    #pragma unroll
    for(int vv=0;vv<9;vv++){
      const float y=xin[vv][d]*g2[vv*512+d];
      const float vval=(y-muv[vv])*rsv[vv]*rn_scale[vv*512+d]+rn_bias[vv*512+d];
      o=fmaf(vval,wsmx[vv],o);
    }
    obuf[d]=o;
  }
  __syncthreads();
  float sa=0.f, sb=0.f;
  for(int d=tid;d<512;d+=256){ const float v=obuf[d]; sa+=v; sb+=v*v; }
  const float2 s2=blockReduceSum2(sa, sb, red);
  const float mu2=s2.x*(1.f/512.f);
  const float var2=s2.y*(1.f/512.f)-mu2*mu2;
  const float rstd2=rsqrtf(var2+1e-5f);
  for(int d=tid;d<512;d+=256) orow[d]=(obuf[d]-mu2)*rstd2*lns[d]+lnb[d];
}

// ---------------- one LSTM recurrence step (256 blocks, weights+h LDS-staged) ----------------
__global__ __launch_bounds__(256) void k_lstm_s(const float* __restrict__ xproj, const float* __restrict__ whh,
     const float* __restrict__ hr, float* __restrict__ hw, float* __restrict__ cg, int t){
  __shared__ float wlds[8][516];
  __shared__ float hlds[32][516];
  __shared__ float gv[32][9];
  const int bid=blockIdx.x, tid=threadIdx.x;
  const int j0=bid*2;
  for(int idx=tid; idx<1024; idx+=256){
    const int r2=idx>>7, k4=(idx&127)*4;
    const int gate2=r2>>1, jl2=r2&1;
    *(float4*)&wlds[r2][k4] = *(const float4*)&whh[(size_t)(gate2*512 + j0 + jl2)*512 + k4];
  }
  if(t>0){
    for(int idx=tid; idx<4096; idx+=256){
      const int rb=idx>>7, k4=(idx&127)*4;
      *(float4*)&hlds[rb][k4] = *(const float4*)&hr[rb*512+k4];
    }
  }
  __syncthreads();
  const int r=tid&7, b=tid>>3;
  const int gate=r>>1, jloc=r&1;
  float acc = xproj[((size_t)b*12+t)*2048 + gate*512 + j0 + jloc];
  if(t>0){
    float4 s={0.f,0.f,0.f,0.f};
    for(int k=0;k<512;k+=4){
      const float4 hk=*(const float4*)&hlds[b][k];
      const float4 wk=*(const float4*)&wlds[r][k];
      s.x=fmaf(hk.x,wk.x,s.x); s.y=fmaf(hk.y,wk.y,s.y);
      s.z=fmaf(hk.z,wk.z,s.z); s.w=fmaf(hk.w,wk.w,s.w);
    }
    acc+=(s.x+s.y)+(s.z+s.w);
  }
  gv[b][r]=acc;
  __syncthreads();
  if(tid<64){
    const int bb=tid>>1, jj=tid&1;
    const float gi=gv[bb][0+jj], gf=gv[bb][2+jj], gg=gv[bb][4+jj], go=gv[bb][6+jj];
    float c = (t==0) ? 0.f : cg[bb*512 + j0 + jj];
    c = sigm(gf)*c + sigm(gi)*tanhf(gg);
    cg[bb*512 + j0 + jj]=c;
    hw[bb*512 + j0 + jj]=sigm(go)*tanhf(c);
  }
}

// ---------------- decoder single-step LSTM (zero state), uses bsum ----------------
__global__ __launch_bounds__(256) void k_declstm(const float* __restrict__ Xc1, const float* __restrict__ wih,
        const float* __restrict__ bsum, float* __restrict__ hout){
  __shared__ float xs_[32][516];
  const int n=blockIdx.x, tid=threadIdx.x;
  for(int idx=tid; idx<16384; idx+=256){
    const int bb=idx>>9, k=idx&511;
    xs_[bb][k]=Xc1[bb*512+k];
  }
  __syncthreads();
  const int jl=tid>>4, bl=tid&15;
  const int j=n*16+jl;
  const float* wi=wih+(size_t)j*512;
  const float* wg=wih+(size_t)(1024+j)*512;
  const float* wo=wih+(size_t)(1536+j)*512;
  const float bi_=bsum[j];
  const float bg_=bsum[1024+j];
  const float bo_=bsum[1536+j];
  #pragma unroll
  for(int half=0; half<2; half++){
    const int b=bl+half*16;
    float gi=bi_, gg=bg_, go=bo_;
    for(int k=0;k<512;k+=4){
      const float4 xk=*(const float4*)&xs_[b][k];
      const float4 a0=*(const float4*)(wi+k);
      const float4 a1=*(const float4*)(wg+k);
      const float4 a2=*(const float4*)(wo+k);
      gi += xk.x*a0.x+xk.y*a0.y+xk.z*a0.z+xk.w*a0.w;
      gg += xk.x*a1.x+xk.y*a1.y+xk.z*a1.z+xk.w*a1.w;
      go += xk.x*a2.x+xk.y*a2.y+xk.z*a2.z+xk.w*a2.w;
    }
    const float c=sigm(gi)*tanhf(gg);
    hout[b*512+j]=sigm(go)*tanhf(c);
  }
}

// ---------------- fused ydec + decoder varsel (per-batch; grid 32) ----------------
__global__ __launch_bounds__(256) void k_ydvs(
  int l,
  const float* __restrict__ hb, const float* __restrict__ Xcov, const float* __restrict__ cov_w,
  const float* __restrict__ Xs, const float* __restrict__ g2,
  const float* __restrict__ rn_scale, const float* __restrict__ rn_bias,
  const float* __restrict__ fc1_w, const float* __restrict__ fc1_b,
  const float* __restrict__ fc2_w, const float* __restrict__ fc2_b,
  const float* __restrict__ glu_w, const float* __restrict__ glu_b,
  const float* __restrict__ grn_s, const float* __restrict__ grn_b,
  const float* __restrict__ rs_gate, const float* __restrict__ rs_scale, const float* __restrict__ rs_bias,
  const float* __restrict__ ln2s, const float* __restrict__ ln2b,
  const float* __restrict__ ln3s, const float* __restrict__ ln3b,
  float* __restrict__ outX, float* __restrict__ wgt_base, unsigned short* __restrict__ yembB)
{
  __shared__ float xin[9][512];
  __shared__ float red[256];
  __shared__ float obuf[512];
  __shared__ float ydl[512];
  __shared__ float muv[9], rsv[9], wsmx[9], hbuf9[9];
  const int tid=threadIdx.x, b=blockIdx.x;
  const float* xs=Xs+((size_t)b*18+12+l)*512;
  for(int d=tid;d<512;d+=256) obuf[d]=hb[b*512+d];
  __syncthreads();
  {
    float sa=0.f, sb=0.f;
    for(int d=tid;d<512;d+=256){ const float v=obuf[d]; sa+=v; sb+=v*v; }
    const float2 s2=blockReduceSum2(sa, sb, red);
    const float mu=s2.x*(1.f/512.f);
    const float var=s2.y*(1.f/512.f)-mu*mu;
    const float rstd=rsqrtf(var+1e-5f);
    for(int d=tid;d<512;d+=256){
      const float o=(obuf[d]-mu)*rstd*ln2s[d]+ln2b[d]+xs[d];
      ydl[d]=o;
      yembB[((size_t)b*6+l)*512+d]=f2b(o);
    }
  }
  __syncthreads();
  if(l==5) return;
  const float* covrow=Xcov+((size_t)b*12+11)*8;
  float* orow=outX+(size_t)b*512;
  float* wp=wgt_base+b*54+(l+1)*9;
  for(int idx=tid; idx<4608; idx+=256){
    const int vv=idx>>9, d=idx&511;
    const float base=xs[d];
    xin[vv][d] = (vv==0) ? (ydl[d]+base) : fmaf(covrow[vv-1], cov_w[(vv-1)*512+d], base);
  }
  __syncthreads();
  {
    float sa9[9], sb9[9];
    const int d0=tid*2;
    #pragma unroll
    for(int vv=0;vv<9;vv++){
      const float y0=xin[vv][d0]  *g2[vv*512+d0];
      const float y1=xin[vv][d0+1]*g2[vv*512+d0+1];
      sa9[vv]=y0+y1; sb9[vv]=y0*y0+y1*y1;
    }
    #pragma unroll
    for(int off=32; off>0; off>>=1){
      #pragma unroll
      for(int vv=0;vv<9;vv++){
        sa9[vv]+=__shfl_xor(sa9[vv],off);
        sb9[vv]+=__shfl_xor(sb9[vv],off);
      }
    }
    const int wid=tid>>6;
    if((tid&63)==0){
      #pragma unroll
      for(int vv=0;vv<9;vv++){ red[wid*18+vv]=sa9[vv]; red[wid*18+9+vv]=sb9[vv]; }
    }
    __syncthreads();
    if(tid<9){
      const float sA=red[tid]+red[18+tid]+red[36+tid]+red[54+tid];
      const float sB=red[9+tid]+red[27+tid]+red[45+tid]+red[63+tid];
      const float mu=sA*(1.f/512.f);
      const float var=sB*(1.f/512.f)-mu*mu;
      muv[tid]=mu; rsv[tid]=rsqrtf(var+1e-5f);
    }
  }
  {
    float hp[9]={0,0,0,0,0,0,0,0,0};
    const float* flat=&xin[0][0];
    for(int i=tid;i<4608;i+=256){
      const float f=flat[i];
      #pragma unroll
      for(int j=0;j<9;j++) hp[j]=fmaf(f, fc1_w[j*4608+i], hp[j]);
    }
    #pragma unroll
    for(int off=32; off>0; off>>=1){
      #pragma unroll
      for(int j=0;j<9;j++) hp[j]+=__shfl_xor(hp[j],off);
    }
    const int wid=tid>>6;
    __syncthreads();
    if((tid&63)==0){
      #pragma unroll
      for(int j=0;j<9;j++) red[wid*9+j]=hp[j];
    }
    __syncthreads();
    if(tid<9) hbuf9[tid]=red[tid]+red[9+tid]+red[18+tid]+red[27+tid];
    __syncthreads();
  }
  if(tid==0){
    const float* flat=&xin[0][0];
    float rg[9];
    #pragma unroll
    for(int k=0;k<9;k++){
      const float pos=(float)k*575.875f;
      const int lo=(int)floorf(pos);
      const float fr=pos-(float)lo;
      int hi=lo+1; if(hi>4607)hi=4607;
      rg[k]=(flat[lo]*(1.f-fr)+flat[hi]*fr)*2.f*sigm(rs_gate[k]);
    }
    float mu=0.f; for(int k=0;k<9;k++) mu+=rg[k]; mu*=(1.f/9.f);
    float va=0.f; for(int k=0;k<9;k++){const float dd=rg[k]-mu; va+=dd*dd;} va*=(1.f/9.f);
    float rstd=rsqrtf(va+1e-5f);
    float resv[9];
    for(int k=0;k<9;k++) resv[k]=(rg[k]-mu)*rstd*rs_scale[k]+rs_bias[k];
    float h[9];
    for(int j=0;j<9;j++){ const float x=hbuf9[j]+fc1_b[j]; h[j]=x>0.f?x:expm1f(x); }
    float h2[9];
    for(int j=0;j<9;j++){ float s=fc2_b[j]; for(int k=0;k<9;k++) s=fmaf(h[k],fc2_w[j*9+k],s); h2[j]=s; }
    float lg[9];
    for(int j=0;j<9;j++){
      float sa=glu_b[j];   for(int k=0;k<9;k++) sa=fmaf(h2[k],glu_w[j*9+k],sa);
      float sg=glu_b[9+j]; for(int k=0;k<9;k++) sg=fmaf(h2[k],glu_w[(9+j)*9+k],sg);
      lg[j]=sa*sigm(sg)+resv[j];
    }
    mu=0.f; for(int k=0;k<9;k++) mu+=lg[k]; mu*=(1.f/9.f);
    va=0.f; for(int k=0;k<9;k++){const float dd=lg[k]-mu; va+=dd*dd;} va*=(1.f/9.f);
    rstd=rsqrtf(va+1e-5f);
    float lnv[9], mx=-1e30f;
    for(int k=0;k<9;k++){ lnv[k]=(lg[k]-mu)*rstd*grn_s[k]+grn_b[k]; mx=fmaxf(mx,lnv[k]); }
    float se=0.f;
    for(int k=0;k<9;k++){ lnv[k]=expf(lnv[k]-mx); se+=lnv[k]; }
    const float inv=1.f/se;
    for(int k=0;k<9;k++){ const float w=lnv[k]*inv; wsmx[k]=w; wp[k]=w; }
  }
  __syncthreads();
  for(int d=tid; d<512; d+=256){
    float o=0.f;
    #pragma unroll
    for(int vv=0;vv<9;vv++){
      const float y=xin[vv][d]*g2[vv*512+d];
      const float vval=(y-muv[vv])*rsv[vv]*rn_scale[vv*512+d]+rn_bias[vv*512+d];
      o=fmaf(vval,wsmx[vv],o);
    }
    obuf[d]=o;
  }
  __syncthreads();
  float sa=0.f, sb=0.f;
  for(int d=tid;d<512;d+=256){ const float v=obuf[d]; sa+=v; sb+=v*v; }
  const float2 s2=blockReduceSum2(sa, sb, red);
  const float mu2=s2.x*(1.f/512.f);
  const float var2=s2.y*(1.f/512.f)-mu2*mu2;
  const float rstd2=rsqrtf(var2+1e-5f);
  for(int d=tid;d<512;d+=256) orow[d]=(obuf[d]-mu2)*rstd2*ln3s[d]+ln3b[d];
}

extern "C" void kernel_launch(void* const* d_in, const int* in_sizes, int n_in,
                              void* d_out, int out_size, void* d_ws, size_t ws_size,
                              hipStream_t stream){
  (void)in_sizes; (void)n_in; (void)out_size; (void)ws_size;
  const float* Xauto=(const float*)d_in[0];
  const float* Xcov =(const float*)d_in[1];
  const float* Xstat=(const float*)d_in[2];
  const float* xmask=(const float*)d_in[3];
  const float* c1w=(const float*)d_in[4];
  const float* c1b=(const float*)d_in[5];
  const float* c2w=(const float*)d_in[6];
  const float* c2b=(const float*)d_in[7];
  const float* c3w=(const float*)d_in[8];
  const float* c3b=(const float*)d_in[9];
  const float* cov_w=(const float*)d_in[10];
  const float* static_w=(const float*)d_in[11];
  const float* rn_gate=(const float*)d_in[12];
  const float* rn_scale=(const float*)d_in[13];
  const float* rn_bias=(const float*)d_in[14];
  const float* fc1_w=(const float*)d_in[15];
  const float* fc1_b=(const float*)d_in[16];
  const float* fc2_w=(const float*)d_in[17];
  const float* fc2_b=(const float*)d_in[18];
  const float* glu_w=(const float*)d_in[19];
  const float* glu_b=(const float*)d_in[20];
  const float* grn_s=(const float*)d_in[21];
  const float* grn_b=(const float*)d_in[22];
  const float* rs_gate=(const float*)d_in[23];
  const float* rs_scale=(const float*)d_in[24];
  const float* rs_bias=(const float*)d_in[25];
  const float* ln1s=(const float*)d_in[26];
  const float* ln1b=(const float*)d_in[27];
  const float* ln2s=(const float*)d_in[28];
  const float* ln2b=(const float*)d_in[29];
  const float* ln3s=(const float*)d_in[30];
  const float* ln3b=(const float*)d_in[31];
  const float* wih=(const float*)d_in[32];
  const float* whh=(const float*)d_in[33];
  const float* bih=(const float*)d_in[34];
  const float* bhh=(const float*)d_in[35];
  const float* head_w=(const float*)d_in[36];
  const float* head_b=(const float*)d_in[37];

  float* out=(float*)d_out;
  float* ws=(float*)d_ws;
  unsigned short* A2=(unsigned short*)((char*)d_ws + WS_ENDF*sizeof(float));
  float* part=(float*)((char*)d_ws + WS_ENDF*sizeof(float) + A2_BYTES);
  unsigned short* yembB=(unsigned short*)(ws+WS_YEMBB);
  float* g2=ws+WS_YDEC;            // 4608 floats
  float* bsum=ws+WS_YDEC+8192;     // 2048 floats

  const dim3 blk(256);
  k_pre<<<1154,blk,0,stream>>>(xmask, c1w, c1b, c2w, rn_gate, bih, bhh, Xstat, static_w,
                               ws, ws+WS_W12, ws+WS_W12+4096, g2, bsum, ws+WS_XS);
  k_conv12<<<384,blk,0,stream>>>(Xauto, xmask, ws, ws+WS_W12, ws+WS_W12+4096, c2b, A2);
  // conv3 split-K: BM=384 (c3w read once), BN=128, BK=64, z=64 chunks of 2048.
  // NT=1024: 16 waves per block -> doubles waves/CU at the 1-block/CU (128KB LDS) occupancy point.
  k_mfma<1,384,128,1024><<<dim3(4,1,64),dim3(1024),0,stream>>>(A2, c3w, part, nullptr);
  // varsel with fused split-K reduce + pconv epilogue
  k_varsel<<<384,blk,0,stream>>>(part, c3b, ws, Xcov, cov_w, ws+WS_XS, g2,
      rn_scale,rn_bias, fc1_w,fc1_b,fc2_w,fc2_b, glu_w,glu_b, grn_s,grn_b,
      rs_gate,rs_scale,rs_bias, ln1s,ln1b, ws+WS_XCUR, out+YN);
  // xproj via MFMA (MODE 3): A=Xcur f32 reg-cvt, B=wih, bias=bsum
  k_mfma<3,192,128,512><<<dim3(16,2),dim3(512),0,stream>>>(
      (const unsigned short*)(const void*)(ws+WS_XCUR), wih, ws+WS_XPROJ, bsum);
  for(int t=0;t<12;t++){
    const float* hr = ws + ((t&1) ? WS_HB1 : WS_HB0);
    float* hw = ws + ((t&1) ? WS_HB0 : WS_HB1);
    k_lstm_s<<<256,blk,0,stream>>>(ws+WS_XPROJ, whh, hr, hw, ws+WS_CB, t);
  }
  for(int l=0;l<6;l++){
    if(l>0){
      k_declstm<<<32,blk,0,stream>>>(ws+WS_XC1, wih, bsum, ws+WS_HB0);
    }
    k_ydvs<<<32,blk,0,stream>>>(l, ws+WS_HB0, Xcov, cov_w, ws+WS_XS, g2,
        rn_scale,rn_bias, fc1_w,fc1_b,fc2_w,fc2_b, glu_w,glu_b, grn_s,grn_b,
        rs_gate,rs_scale,rs_bias, ln2s,ln2b, ln3s,ln3b,
        ws+WS_XC1, out+YN, yembB);
  }
  // head: BM=192, BN=128, BK=64 -> 80KB LDS = 2 blocks/CU, head_w read once
  k_mfma<2,192,128,512><<<dim3(1024,1),dim3(512),0,stream>>>(yembB, head_w, out, head_b);
}